// Round 4
// baseline (147.754 us; speedup 1.0000x reference)
//
#include <hip/hip_runtime.h>
#include <math.h>

typedef unsigned short u16;
typedef __attribute__((ext_vector_type(8))) short short8;
typedef __attribute__((ext_vector_type(4))) short short4v;
typedef __attribute__((ext_vector_type(4))) float floatx4;
typedef __attribute__((ext_vector_type(2))) unsigned int uint2v;

#define SEQ 1024
#define CDIM 384
#define NH 8
#define DH 48
#define DP 64   // padded head dim for Q/K storage
#define NB 8

__device__ __forceinline__ u16 f2bf(float f){
  unsigned int u; __builtin_memcpy(&u, &f, 4);
  u = (u + 0x7fffu + ((u >> 16) & 1u)) >> 16;
  return (u16)u;
}

union Pack4 { u16 u[4]; uint2v v2; short4v s4; };

// ---------------- Kernel 0: fp32 -> bf16 weight conversion ----------------
__global__ __launch_bounds__(256) void cvt_f32_bf16(const float* __restrict__ src,
                                                    u16* __restrict__ dst, int n){
  const int i = (blockIdx.x * 256 + threadIdx.x) * 4;
  if (i + 3 < n){
    float4 f = *(const float4*)(src + i);
    dst[i + 0] = f2bf(f.x);
    dst[i + 1] = f2bf(f.y);
    dst[i + 2] = f2bf(f.z);
    dst[i + 3] = f2bf(f.w);
  }
}

// ---------------- Kernel 1: transpose x[b][c][s] (fp32) -> xT[b][s][c] (bf16) ----------------
__global__ __launch_bounds__(256) void transpose_x(const float* __restrict__ x,
                                                   u16* __restrict__ xT){
  const int b = blockIdx.z;
  const int c0 = blockIdx.y * 64;
  const int s0 = blockIdx.x * 128;
  const int t = threadIdx.x;
  const int w = t >> 6, l = t & 63;
  const int c = c0 + l;
  const float* src = x + ((size_t)(b * CDIM + c)) * SEQ + s0 + w * 32;
  u16* dst = xT + ((size_t)(b * SEQ + s0 + w * 32)) * CDIM + c;
#pragma unroll
  for (int i = 0; i < 8; i++){
    float4 f = *(const float4*)(src + i * 4);
    dst[(size_t)(i * 4 + 0) * CDIM] = f2bf(f.x);
    dst[(size_t)(i * 4 + 1) * CDIM] = f2bf(f.y);
    dst[(size_t)(i * 4 + 2) * CDIM] = f2bf(f.z);
    dst[(size_t)(i * 4 + 3) * CDIM] = f2bf(f.w);
  }
}

// ---------------- Kernel 2: QKV GEMM  qkv[o][s] = W[o][c] * xT[s][c]^T ----------------
// Q[pair][s][64] (cols 48..63 zero, pre-scaled by d^-0.5*log2e)
// K[pair][s][64] (cols 48..63 zero)
// Vt[pair][48][s]
__global__ __launch_bounds__(256) void qkv_kernel(const u16* __restrict__ W,
                                                  const u16* __restrict__ xT,
                                                  u16* __restrict__ qws,
                                                  u16* __restrict__ kws,
                                                  u16* __restrict__ vws){
  __shared__ u16 ldsA[128 * 32];
  __shared__ u16 ldsB[64 * 32];
  const int t = threadIdx.x;
  const int w = t >> 6, l = t & 63;
  const int quad = l >> 4, li = l & 15;
  const int n0 = blockIdx.x * 64;
  const int m0 = blockIdx.y * 128;
  const int b  = blockIdx.z;

  floatx4 acc[2][4];
#pragma unroll
  for (int mt = 0; mt < 2; mt++)
#pragma unroll
    for (int nt = 0; nt < 4; nt++) acc[mt][nt] = (floatx4)0.0f;

  const u16* xb = xT + (size_t)b * SEQ * CDIM;

  const int ar = t >> 1, ac = (t & 1) * 16;  // ldsA staging: 128 rows x 32
  const int br = t >> 2, bc = (t & 3) * 8;   // ldsB staging: 64 rows x 32

  for (int kk = 0; kk < CDIM; kk += 32){
    short8 a0 = *(const short8*)&W[(size_t)(m0 + ar) * CDIM + kk + ac];
    short8 a1 = *(const short8*)&W[(size_t)(m0 + ar) * CDIM + kk + ac + 8];
    short8 b0 = *(const short8*)&xb[(size_t)(n0 + br) * CDIM + kk + bc];
    __syncthreads();   // previous iteration's fragment reads done
    *(short8*)&ldsA[ar * 32 + ac]     = a0;
    *(short8*)&ldsA[ar * 32 + ac + 8] = a1;
    *(short8*)&ldsB[br * 32 + bc]     = b0;
    __syncthreads();   // stores visible
    short8 af[2], bfr[4];
#pragma unroll
    for (int mt = 0; mt < 2; mt++)
      af[mt] = *(const short8*)&ldsA[(w * 32 + mt * 16 + li) * 32 + quad * 8];
#pragma unroll
    for (int nt = 0; nt < 4; nt++)
      bfr[nt] = *(const short8*)&ldsB[(nt * 16 + li) * 32 + quad * 8];
#pragma unroll
    for (int mt = 0; mt < 2; mt++)
#pragma unroll
      for (int nt = 0; nt < 4; nt++)
        acc[mt][nt] = __builtin_amdgcn_mfma_f32_16x16x32_bf16(af[mt], bfr[nt], acc[mt][nt], 0, 0, 0);
  }

  const float qs = 0.14433756729740643f * 1.4426950408889634f; // d^-0.5 * log2(e)
  const uint2v z2 = (uint2v)0u;
#pragma unroll
  for (int mt = 0; mt < 2; mt++){
    const int obase = m0 + w * 32 + mt * 16 + quad * 4;
    const int which = obase / CDIM;          // uniform per 4-row group (384 % 4 == 0)
    const int rem = obase - which * CDIM;
    const int h = rem / DH;                  // uniform per 4-row group (48 % 4 == 0)
    const int dd = rem - h * DH;             // includes quad*4
    const int pair = b * NH + h;
#pragma unroll
    for (int nt = 0; nt < 4; nt++){
      const int s = n0 + nt * 16 + li;
      floatx4 v = acc[mt][nt];
      if (which == 0){
        Pack4 pk;
#pragma unroll
        for (int r = 0; r < 4; r++) pk.u[r] = f2bf(v[r] * qs);
        *(uint2v*)&qws[((size_t)pair * SEQ + s) * DP + dd] = pk.v2;
        if ((dd & 48) == 32)
          *(uint2v*)&qws[((size_t)pair * SEQ + s) * DP + dd + 16] = z2;
      } else if (which == 1){
        Pack4 pk;
#pragma unroll
        for (int r = 0; r < 4; r++) pk.u[r] = f2bf(v[r]);
        *(uint2v*)&kws[((size_t)pair * SEQ + s) * DP + dd] = pk.v2;
        if ((dd & 48) == 32)
          *(uint2v*)&kws[((size_t)pair * SEQ + s) * DP + dd + 16] = z2;
      } else {
#pragma unroll
        for (int r = 0; r < 4; r++)
          vws[((size_t)pair * DH + dd + r) * SEQ + s] = f2bf(v[r]);
      }
    }
  }
}

// ---------------- Kernel 3: flash attention (S^T formulation) ----------------
// block = 8 waves x 16 Q-rows = 128 Q rows; KV tiles of 128
__global__ __launch_bounds__(512) void attn_kernel(const u16* __restrict__ qws,
                                                   const u16* __restrict__ kws,
                                                   const u16* __restrict__ vws,
                                                   u16* __restrict__ aT){
  __shared__ u16 ldsKP[128 * 136];   // K tile [128][72] / P tiles [128][136] (phase-aliased)
  __shared__ u16 ldsV[48 * 136];

  const int t = threadIdx.x;
  const int w = t >> 6, l = t & 63;
  const int quad = l >> 4, li = l & 15;
  const int pair = blockIdx.y;
  const int b = pair >> 3, h = pair & 7;
  const int m0 = blockIdx.x * 128 + w * 16;

  // Q fragments (B-operand): lane li = query row m0+li, k = quad*8+j (row stride 64, 48..63 zero)
  const u16* qrow = qws + ((size_t)pair * SEQ + m0 + li) * DP;
  const short8 qf0 = *(const short8*)(qrow + quad * 8);
  const short8 qf1 = *(const short8*)(qrow + 32 + quad * 8);

  floatx4 ot[3];
#pragma unroll
  for (int dt = 0; dt < 3; dt++) ot[dt] = (floatx4)0.0f;
  float m_run = -3.0e38f, l_run = 0.0f;
  u16* prow = ldsKP + (w * 16 + li) * 136;

  for (int kv0 = 0; kv0 < SEQ; kv0 += 128){
    // ---- stage K [128][64->72] and V [48][128->136] via registers ----
    uint2v kreg[4], vreg[3];
#pragma unroll
    for (int rep = 0; rep < 4; rep++){
      const int lin = rep * 512 + t;
      const int row = lin >> 4, colc = (lin & 15) << 2;
      kreg[rep] = *(const uint2v*)&kws[((size_t)pair * SEQ + kv0 + row) * DP + colc];
    }
#pragma unroll
    for (int rep = 0; rep < 3; rep++){
      const int lin = rep * 512 + t;
      const int d = lin >> 5, y4 = (lin & 31) << 2;
      vreg[rep] = *(const uint2v*)&vws[((size_t)pair * DH + d) * SEQ + kv0 + y4];
    }
    __syncthreads();   // previous iteration's P and V reads complete
#pragma unroll
    for (int rep = 0; rep < 4; rep++){
      const int lin = rep * 512 + t;
      const int row = lin >> 4, colc = (lin & 15) << 2;
      *(uint2v*)&ldsKP[row * 72 + colc] = kreg[rep];
    }
#pragma unroll
    for (int rep = 0; rep < 3; rep++){
      const int lin = rep * 512 + t;
      const int d = lin >> 5, y4 = (lin & 31) << 2;
      *(uint2v*)&ldsV[d * 136 + y4] = vreg[rep];
    }
    __syncthreads();   // K,V visible

    // ---- S^T[y][m] = K[y][:] . Q[m][:] ----
    floatx4 st[8];
#pragma unroll
    for (int yt = 0; yt < 8; yt++){
      const u16* krow = ldsKP + (yt * 16 + li) * 72;
      const short8 kf0 = *(const short8*)(krow + quad * 8);
      const short8 kf1 = *(const short8*)(krow + 32 + quad * 8);
      floatx4 z = (floatx4)0.0f;
      z = __builtin_amdgcn_mfma_f32_16x16x32_bf16(kf0, qf0, z, 0, 0, 0);
      z = __builtin_amdgcn_mfma_f32_16x16x32_bf16(kf1, qf1, z, 0, 0, 0);
      st[yt] = z;
    }

    // ---- online softmax; per-query stats live in lane&15, reduce over quads ----
    float mx = -3.0e38f;
#pragma unroll
    for (int yt = 0; yt < 8; yt++)
#pragma unroll
      for (int r = 0; r < 4; r++) mx = fmaxf(mx, st[yt][r]);
    mx = fmaxf(mx, __shfl_xor(mx, 16, 64));
    mx = fmaxf(mx, __shfl_xor(mx, 32, 64));
    const float mnew = fmaxf(m_run, mx);
    const float alpha = exp2f(m_run - mnew);
    m_run = mnew;
    float ls = 0.0f;
#pragma unroll
    for (int yt = 0; yt < 8; yt++)
#pragma unroll
      for (int r = 0; r < 4; r++){
        const float p = exp2f(st[yt][r] - mnew);
        st[yt][r] = p; ls += p;
      }
    ls += __shfl_xor(ls, 16, 64);
    ls += __shfl_xor(ls, 32, 64);
    l_run = l_run * alpha + ls;
#pragma unroll
    for (int dt = 0; dt < 3; dt++) ot[dt] *= alpha;

    __syncthreads();   // all waves done reading K before P overwrites the region

    // ---- P -> LDS (row = query, col = key) ----
#pragma unroll
    for (int yt = 0; yt < 8; yt++){
      Pack4 pk;
#pragma unroll
      for (int r = 0; r < 4; r++) pk.u[r] = f2bf(st[yt][r]);
      *(short4v*)&prow[yt * 16 + quad * 4] = pk.s4;
    }
    __syncthreads();   // P stores ordered before P reads

    // ---- O^T[d][m] += Vt[d][y] . P[y][m] ----
#pragma unroll
    for (int ks = 0; ks < 128; ks += 32){
      const short8 pb = *(const short8*)&prow[ks + quad * 8];
#pragma unroll
      for (int dt = 0; dt < 3; dt++){
        const short8 vf = *(const short8*)&ldsV[(dt * 16 + li) * 136 + ks + quad * 8];
        ot[dt] = __builtin_amdgcn_mfma_f32_16x16x32_bf16(vf, pb, ot[dt], 0, 0, 0);
      }
    }
  }

  const float rl = 1.0f / l_run;
  const int sg = m0 + li;
#pragma unroll
  for (int dt = 0; dt < 3; dt++){
    Pack4 pk;
#pragma unroll
    for (int r = 0; r < 4; r++) pk.u[r] = f2bf(ot[dt][r] * rl);
    *(uint2v*)&aT[((size_t)b * SEQ + sg) * CDIM + h * DH + dt * 16 + quad * 4] = pk.v2;
  }
}

// ---------------- Kernel 4: proj GEMM  out[o][s] = Wp[o][c] * attnT[s][c]^T + bias (fp32 out) ----------------
__global__ __launch_bounds__(256) void proj_kernel(const u16* __restrict__ W,
                                                   const u16* __restrict__ aT,
                                                   const float* __restrict__ bias,
                                                   float* __restrict__ out){
  __shared__ u16 ldsA[128 * 32];
  __shared__ u16 ldsB[64 * 32];
  const int t = threadIdx.x;
  const int w = t >> 6, l = t & 63;
  const int quad = l >> 4, li = l & 15;
  const int n0 = blockIdx.x * 64;
  const int m0 = blockIdx.y * 128;
  const int b  = blockIdx.z;

  floatx4 acc[2][4];
#pragma unroll
  for (int mt = 0; mt < 2; mt++)
#pragma unroll
    for (int nt = 0; nt < 4; nt++) acc[mt][nt] = (floatx4)0.0f;

  const u16* ab = aT + (size_t)b * SEQ * CDIM;

  const int ar = t >> 1, ac = (t & 1) * 16;
  const int br = t >> 2, bc = (t & 3) * 8;

  for (int kk = 0; kk < CDIM; kk += 32){
    short8 a0 = *(const short8*)&W[(size_t)(m0 + ar) * CDIM + kk + ac];
    short8 a1 = *(const short8*)&W[(size_t)(m0 + ar) * CDIM + kk + ac + 8];
    short8 b0 = *(const short8*)&ab[(size_t)(n0 + br) * CDIM + kk + bc];
    __syncthreads();
    *(short8*)&ldsA[ar * 32 + ac]     = a0;
    *(short8*)&ldsA[ar * 32 + ac + 8] = a1;
    *(short8*)&ldsB[br * 32 + bc]     = b0;
    __syncthreads();
    short8 af[2], bfr[4];
#pragma unroll
    for (int mt = 0; mt < 2; mt++)
      af[mt] = *(const short8*)&ldsA[(w * 32 + mt * 16 + li) * 32 + quad * 8];
#pragma unroll
    for (int nt = 0; nt < 4; nt++)
      bfr[nt] = *(const short8*)&ldsB[(nt * 16 + li) * 32 + quad * 8];
#pragma unroll
    for (int mt = 0; mt < 2; mt++)
#pragma unroll
      for (int nt = 0; nt < 4; nt++)
        acc[mt][nt] = __builtin_amdgcn_mfma_f32_16x16x32_bf16(af[mt], bfr[nt], acc[mt][nt], 0, 0, 0);
  }

#pragma unroll
  for (int mt = 0; mt < 2; mt++){
    const int o0 = m0 + w * 32 + mt * 16 + quad * 4;
    float bs[4];
#pragma unroll
    for (int r = 0; r < 4; r++) bs[r] = bias[o0 + r];
#pragma unroll
    for (int nt = 0; nt < 4; nt++){
      const int s = n0 + nt * 16 + li;
#pragma unroll
      for (int r = 0; r < 4; r++)
        out[((size_t)b * CDIM + o0 + r) * SEQ + s] = acc[mt][nt][r] + bs[r];
    }
  }
}

extern "C" void kernel_launch(void* const* d_in, const int* in_sizes, int n_in,
                              void* d_out, int out_size, void* d_ws, size_t ws_size,
                              hipStream_t stream) {
  const float* x      = (const float*)d_in[0];  // [8][384][1024] fp32
  const float* w_qkv  = (const float*)d_in[1];  // [1152][384] fp32
  const float* w_proj = (const float*)d_in[2];  // [384][384] fp32
  const float* b_proj = (const float*)d_in[3];  // [384] fp32
  float* out = (float*)d_out;                   // [8][384][1024] fp32

  char* ws = (char*)d_ws;
  const size_t SZX = (size_t)NB * SEQ * CDIM * sizeof(u16);       // 6 MB (xT / aT)
  const size_t SZQ = (size_t)NB * NH * SEQ * DP * sizeof(u16);    // 8 MB (padded Q/K)
  const size_t SZV = (size_t)NB * NH * SEQ * DH * sizeof(u16);    // 6 MB
  u16* xT   = (u16*)(ws);
  u16* qws  = (u16*)(ws + SZX);
  u16* kws  = (u16*)(ws + SZX + SZQ);
  u16* vws  = (u16*)(ws + SZX + 2 * SZQ);
  u16* wq_b = (u16*)(ws + SZX + 2 * SZQ + SZV);
  u16* wp_b = wq_b + (size_t)3 * CDIM * CDIM;
  u16* aT   = xT;   // attn output reuses xT (qkv consumed it by then)

  const int n_wq = 3 * CDIM * CDIM;   // 442368
  const int n_wp = CDIM * CDIM;       // 147456
  cvt_f32_bf16<<<dim3((n_wq / 4 + 255) / 256), 256, 0, stream>>>(w_qkv, wq_b, n_wq);
  cvt_f32_bf16<<<dim3((n_wp / 4 + 255) / 256), 256, 0, stream>>>(w_proj, wp_b, n_wp);
  transpose_x<<<dim3(8, 6, 8), 256, 0, stream>>>(x, xT);
  qkv_kernel<<<dim3(16, 9, 8), 256, 0, stream>>>(wq_b, xT, qws, kws, vws);
  attn_kernel<<<dim3(8, 64), 512, 0, stream>>>(qws, kws, vws, aT);
  proj_kernel<<<dim3(16, 3, 8), 256, 0, stream>>>(wp_b, aT, b_proj, out);
}

// Round 6
// 145.900 us; speedup vs baseline: 1.0127x; 1.0127x over previous
//
#include <hip/hip_runtime.h>
#include <math.h>

typedef unsigned short u16;
typedef __attribute__((ext_vector_type(8))) short short8;
typedef __attribute__((ext_vector_type(8))) unsigned short ushort8;
typedef __attribute__((ext_vector_type(4))) float floatx4;
typedef __attribute__((ext_vector_type(2))) unsigned int uint2v;

#define SEQ 1024
#define CDIM 384
#define NH 8
#define DH 48
#define DP 64   // padded head dim for Q/K storage
#define NB 8

__device__ __forceinline__ u16 f2bf(float f){
  unsigned int u; __builtin_memcpy(&u, &f, 4);
  u = (u + 0x7fffu + ((u >> 16) & 1u)) >> 16;
  return (u16)u;
}
// pack two fp32 -> two bf16 (RTNE) in one u32: low16 = a, high16 = b
__device__ __forceinline__ unsigned packbf(float a, float b){
  unsigned ua, ub; __builtin_memcpy(&ua, &a, 4); __builtin_memcpy(&ub, &b, 4);
  ua += 0x7fffu + ((ua >> 16) & 1u);
  ub += 0x7fffu + ((ub >> 16) & 1u);
  return __builtin_amdgcn_perm(ub, ua, 0x07060302);
}
__device__ __forceinline__ void async16(const u16* g, u16* l){
  __builtin_amdgcn_global_load_lds((const __attribute__((address_space(1))) void*)g,
                                   (__attribute__((address_space(3))) void*)l, 16, 0, 0);
}

// ---------------- Kernel 0: fp32 -> bf16 conversion of both weight matrices ----------------
__global__ __launch_bounds__(256) void cvt_weights(const float* __restrict__ wq,
                                                   const float* __restrict__ wp,
                                                   u16* __restrict__ dst){
  const int NWQ = 3 * CDIM * CDIM;  // 442368
  const int i = (blockIdx.x * 256 + threadIdx.x) * 4;
  const float* src = (i < NWQ) ? (wq + i) : (wp + (i - NWQ));
  float4 f = *(const float4*)src;
  unsigned lo = packbf(f.x, f.y), hi = packbf(f.z, f.w);
  uint2v v; v[0] = lo; v[1] = hi;
  *(uint2v*)(dst + i) = v;
}

// ---------------- Kernel 1: transpose x[b][c][s] (fp32) -> xT[b][s][c] (bf16), LDS-tiled ----------------
__global__ __launch_bounds__(256) void transpose_x(const float* __restrict__ x,
                                                   u16* __restrict__ xT){
  __shared__ u16 ldsT[64 * 72];   // [s_local][c_local], stride 72
  const int b = blockIdx.z;
  const int c0 = blockIdx.y * 64;
  const int s0 = blockIdx.x * 64;
  const int t = threadIdx.x;
  const int rr = t >> 2, q4 = t & 3;

  const float* src = x + ((size_t)(b * CDIM + c0 + rr)) * SEQ + s0;
#pragma unroll
  for (int i = 0; i < 4; i++){
    const int cc = q4 + i * 4;
    float4 f = *(const float4*)(src + cc * 4);
    ldsT[(cc * 4 + 0) * 72 + rr] = f2bf(f.x);
    ldsT[(cc * 4 + 1) * 72 + rr] = f2bf(f.y);
    ldsT[(cc * 4 + 2) * 72 + rr] = f2bf(f.z);
    ldsT[(cc * 4 + 3) * 72 + rr] = f2bf(f.w);
  }
  __syncthreads();
  u16* dst = xT + ((size_t)(b * SEQ + s0 + rr)) * CDIM + c0 + q4 * 16;
  *(ushort8*)(dst)     = *(const ushort8*)&ldsT[rr * 72 + q4 * 16];
  *(ushort8*)(dst + 8) = *(const ushort8*)&ldsT[rr * 72 + q4 * 16 + 8];
}

// ---------------- Kernel 2: QKV GEMM (128x128 tile, BK=64, async swizzled staging) ----------------
__global__ __launch_bounds__(256) void qkv_kernel(const u16* __restrict__ W,
                                                  const u16* __restrict__ xT,
                                                  u16* __restrict__ qws,
                                                  u16* __restrict__ kws,
                                                  u16* __restrict__ vws){
  __shared__ u16 ldsA[128 * 64];
  __shared__ u16 ldsB[128 * 64];
  const int t = threadIdx.x;
  const int w = t >> 6, l = t & 63;
  const int quad = l >> 4, li = l & 15;
  const int wm = w >> 1, wn = w & 1;
  const int n0 = blockIdx.x * 128;
  const int m0 = blockIdx.y * 128;
  const int b  = blockIdx.z;

  floatx4 acc[4][4];
#pragma unroll
  for (int i = 0; i < 4; i++)
#pragma unroll
    for (int j = 0; j < 4; j++) acc[i][j] = (floatx4)0.0f;

  const u16* xb = xT + (size_t)b * SEQ * CDIM;
  const int swz = li & 7;

  for (int kk = 0; kk < CDIM; kk += 64){
    __syncthreads();
#pragma unroll
    for (int rep = 0; rep < 4; rep++){
      const int cs = rep * 256 + t;
      const int row = cs >> 3, c4 = cs & 7;
      const int gcol = ((c4 ^ (row & 7)) << 3);
      async16(&W [(size_t)(m0 + row) * CDIM + kk + gcol], &ldsA[cs * 8]);
      async16(&xb[(size_t)(n0 + row) * CDIM + kk + gcol], &ldsB[cs * 8]);
    }
    __syncthreads();
#pragma unroll
    for (int kc = 0; kc < 2; kc++){
      const int rc = ((kc * 4 + quad) ^ swz) << 3;
      short8 af[4], bf[4];
#pragma unroll
      for (int i = 0; i < 4; i++)
        af[i] = *(const short8*)&ldsA[(wm * 64 + i * 16 + li) * 64 + rc];
#pragma unroll
      for (int j = 0; j < 4; j++)
        bf[j] = *(const short8*)&ldsB[(wn * 64 + j * 16 + li) * 64 + rc];
#pragma unroll
      for (int i = 0; i < 4; i++)
#pragma unroll
        for (int j = 0; j < 4; j++)
          acc[i][j] = __builtin_amdgcn_mfma_f32_16x16x32_bf16(af[i], bf[j], acc[i][j], 0, 0, 0);
    }
  }

  const float qs = 0.14433756729740643f * 1.4426950408889634f; // d^-0.5 * log2(e)
  const uint2v z2 = (uint2v)0u;
#pragma unroll
  for (int i = 0; i < 4; i++){
    const int obase = m0 + wm * 64 + i * 16 + quad * 4;
    const int which = obase / CDIM;
    const int rem = obase - which * CDIM;
    const int h = rem / DH;
    const int dd = rem - h * DH;
    const int pair = b * NH + h;
#pragma unroll
    for (int j = 0; j < 4; j++){
      const int s = n0 + wn * 64 + j * 16 + li;
      floatx4 v = acc[i][j];
      if (which == 0){
        uint2v pk; pk[0] = packbf(v[0] * qs, v[1] * qs); pk[1] = packbf(v[2] * qs, v[3] * qs);
        *(uint2v*)&qws[((size_t)pair * SEQ + s) * DP + dd] = pk;
        if ((dd & 48) == 32)
          *(uint2v*)&qws[((size_t)pair * SEQ + s) * DP + dd + 16] = z2;
      } else if (which == 1){
        uint2v pk; pk[0] = packbf(v[0], v[1]); pk[1] = packbf(v[2], v[3]);
        *(uint2v*)&kws[((size_t)pair * SEQ + s) * DP + dd] = pk;
        if ((dd & 48) == 32)
          *(uint2v*)&kws[((size_t)pair * SEQ + s) * DP + dd + 16] = z2;
      } else {
#pragma unroll
        for (int r = 0; r < 4; r++)
          vws[((size_t)pair * DH + dd + r) * SEQ + s] = f2bf(v[r]);
      }
    }
  }
}

// ---------------- Kernel 3: flash attention, S^T form, online-max softmax ----------------
// block = 4 waves x 32 queries = 128 q; KV tiles of 128; grid (8, 64)
__global__ __launch_bounds__(256) void attn_kernel(const u16* __restrict__ qws,
                                                   const u16* __restrict__ kws,
                                                   const u16* __restrict__ vws,
                                                   u16* __restrict__ aT){
  __shared__ u16 ldsK[128 * 64];    // 16 KB, chunk-swizzled ^(row&7)
  __shared__ u16 ldsV[48 * 128];    // 12 KB, chunk-swizzled ^(row&15)
  __shared__ u16 ldsP[128 * 136];   // 34 KB, padded stride

  const int t = threadIdx.x;
  const int w = t >> 6, l = t & 63;
  const int quad = l >> 4, li = l & 15;
  const int pair = blockIdx.y;
  const int b = pair >> 3, h = pair & 7;
  const int qbase = blockIdx.x * 128 + w * 32;
  const int swz = li & 7;

  short8 qf[2][2];
#pragma unroll
  for (int mt = 0; mt < 2; mt++){
    const u16* qrow = qws + ((size_t)pair * SEQ + qbase + mt * 16 + li) * DP;
    qf[mt][0] = *(const short8*)(qrow + quad * 8);
    qf[mt][1] = *(const short8*)(qrow + 32 + quad * 8);
  }

  floatx4 ot[3][2];
#pragma unroll
  for (int dt = 0; dt < 3; dt++)
#pragma unroll
    for (int mt = 0; mt < 2; mt++) ot[dt][mt] = (floatx4)0.0f;
  float m_run[2] = {-3.0e38f, -3.0e38f};
  float l_run[2] = {0.0f, 0.0f};

  const u16* kbase = kws + (size_t)pair * SEQ * DP;
  const u16* vbase = vws + (size_t)pair * DH * SEQ;

  for (int kv0 = 0; kv0 < SEQ; kv0 += 128){
    __syncthreads();
#pragma unroll
    for (int rep = 0; rep < 4; rep++){
      const int cs = rep * 256 + t;
      const int row = cs >> 3, c4 = cs & 7;
      async16(&kbase[(size_t)(kv0 + row) * DP + ((c4 ^ (row & 7)) << 3)], &ldsK[cs * 8]);
    }
#pragma unroll
    for (int rep = 0; rep < 3; rep++){
      const int cs = rep * 256 + t;
      const int row = cs >> 4, c4 = cs & 15;
      async16(&vbase[(size_t)row * SEQ + kv0 + ((c4 ^ (row & 15)) << 3)], &ldsV[cs * 8]);
    }
    __syncthreads();

    // ---- S^T[y][m] = K[y][:] . Q[m][:] ----
    floatx4 st[8][2];
#pragma unroll
    for (int yt = 0; yt < 8; yt++){
      const u16* krow = ldsK + (yt * 16 + li) * 64;
      const short8 kf0 = *(const short8*)(krow + (((0 + quad) ^ swz) << 3));
      const short8 kf1 = *(const short8*)(krow + (((4 + quad) ^ swz) << 3));
#pragma unroll
      for (int mt = 0; mt < 2; mt++){
        floatx4 z = (floatx4)0.0f;
        z = __builtin_amdgcn_mfma_f32_16x16x32_bf16(kf0, qf[mt][0], z, 0, 0, 0);
        z = __builtin_amdgcn_mfma_f32_16x16x32_bf16(kf1, qf[mt][1], z, 0, 0, 0);
        st[yt][mt] = z;
      }
    }

    // ---- online softmax (per-query stats; query = lane&15, quad-reduced) ----
#pragma unroll
    for (int mt = 0; mt < 2; mt++){
      float mx = -3.0e38f;
#pragma unroll
      for (int yt = 0; yt < 8; yt++)
#pragma unroll
        for (int r = 0; r < 4; r++) mx = fmaxf(mx, st[yt][mt][r]);
      mx = fmaxf(mx, __shfl_xor(mx, 16, 64));
      mx = fmaxf(mx, __shfl_xor(mx, 32, 64));
      const float mnew = fmaxf(m_run[mt], mx);
      const float alpha = exp2f(m_run[mt] - mnew);
      m_run[mt] = mnew;

      u16* prow = ldsP + (w * 32 + mt * 16 + li) * 136;
      float ls = 0.0f;
#pragma unroll
      for (int yt = 0; yt < 8; yt++){
        float p0 = exp2f(st[yt][mt][0] - mnew);
        float p1 = exp2f(st[yt][mt][1] - mnew);
        float p2 = exp2f(st[yt][mt][2] - mnew);
        float p3 = exp2f(st[yt][mt][3] - mnew);
        ls += (p0 + p1) + (p2 + p3);
        uint2v pk; pk[0] = packbf(p0, p1); pk[1] = packbf(p2, p3);
        *(uint2v*)&prow[yt * 16 + quad * 4] = pk;
      }
      l_run[mt] = l_run[mt] * alpha + ls;
#pragma unroll
      for (int dt = 0; dt < 3; dt++) ot[dt][mt] *= alpha;
    }
    __syncthreads();   // P visible before PV reads

    // ---- O^T[d][m] += Vt[d][y] . P[y][m] ----
#pragma unroll
    for (int ks = 0; ks < 128; ks += 32){
      short8 pb[2];
#pragma unroll
      for (int mt = 0; mt < 2; mt++)
        pb[mt] = *(const short8*)&ldsP[(w * 32 + mt * 16 + li) * 136 + ks + quad * 8];
#pragma unroll
      for (int dt = 0; dt < 3; dt++){
        const short8 vf = *(const short8*)&ldsV[(dt * 16 + li) * 128 +
                                                ((((ks >> 3) + quad) ^ li) << 3)];
#pragma unroll
        for (int mt = 0; mt < 2; mt++)
          ot[dt][mt] = __builtin_amdgcn_mfma_f32_16x16x32_bf16(vf, pb[mt], ot[dt][mt], 0, 0, 0);
      }
    }
  }

  // cross-quad l reduction and write-out
#pragma unroll
  for (int mt = 0; mt < 2; mt++){
    float ls = l_run[mt];
    ls += __shfl_xor(ls, 16, 64);
    ls += __shfl_xor(ls, 32, 64);
    const float rl = 1.0f / ls;
    const int q = qbase + mt * 16 + li;
#pragma unroll
    for (int dt = 0; dt < 3; dt++){
      floatx4 v = ot[dt][mt];
      uint2v pk; pk[0] = packbf(v[0] * rl, v[1] * rl); pk[1] = packbf(v[2] * rl, v[3] * rl);
      *(uint2v*)&aT[((size_t)b * SEQ + q) * CDIM + h * DH + dt * 16 + quad * 4] = pk;
    }
  }
}

// ---------------- Kernel 4: proj GEMM (128x128 tile, BK=64, async), fp32 out + bias ----------------
__global__ __launch_bounds__(256) void proj_kernel(const u16* __restrict__ W,
                                                   const u16* __restrict__ aT,
                                                   const float* __restrict__ bias,
                                                   float* __restrict__ out){
  __shared__ u16 ldsA[128 * 64];
  __shared__ u16 ldsB[128 * 64];
  const int t = threadIdx.x;
  const int w = t >> 6, l = t & 63;
  const int quad = l >> 4, li = l & 15;
  const int wm = w >> 1, wn = w & 1;
  const int n0 = blockIdx.x * 128;
  const int m0 = blockIdx.y * 128;
  const int b  = blockIdx.z;

  floatx4 acc[4][4];
#pragma unroll
  for (int i = 0; i < 4; i++)
#pragma unroll
    for (int j = 0; j < 4; j++) acc[i][j] = (floatx4)0.0f;

  const u16* ab = aT + (size_t)b * SEQ * CDIM;
  const int swz = li & 7;

  for (int kk = 0; kk < CDIM; kk += 64){
    __syncthreads();
#pragma unroll
    for (int rep = 0; rep < 4; rep++){
      const int cs = rep * 256 + t;
      const int row = cs >> 3, c4 = cs & 7;
      const int gcol = ((c4 ^ (row & 7)) << 3);
      async16(&W [(size_t)(m0 + row) * CDIM + kk + gcol], &ldsA[cs * 8]);
      async16(&ab[(size_t)(n0 + row) * CDIM + kk + gcol], &ldsB[cs * 8]);
    }
    __syncthreads();
#pragma unroll
    for (int kc = 0; kc < 2; kc++){
      const int rc = ((kc * 4 + quad) ^ swz) << 3;
      short8 af[4], bf[4];
#pragma unroll
      for (int i = 0; i < 4; i++)
        af[i] = *(const short8*)&ldsA[(wm * 64 + i * 16 + li) * 64 + rc];
#pragma unroll
      for (int j = 0; j < 4; j++)
        bf[j] = *(const short8*)&ldsB[(wn * 64 + j * 16 + li) * 64 + rc];
#pragma unroll
      for (int i = 0; i < 4; i++)
#pragma unroll
        for (int j = 0; j < 4; j++)
          acc[i][j] = __builtin_amdgcn_mfma_f32_16x16x32_bf16(af[i], bf[j], acc[i][j], 0, 0, 0);
    }
  }

#pragma unroll
  for (int i = 0; i < 4; i++){
    const int o0 = m0 + wm * 64 + i * 16 + quad * 4;
    float bs[4];
#pragma unroll
    for (int r = 0; r < 4; r++) bs[r] = bias[o0 + r];
#pragma unroll
    for (int j = 0; j < 4; j++){
      const int s = n0 + wn * 64 + j * 16 + li;
#pragma unroll
      for (int r = 0; r < 4; r++)
        out[((size_t)b * CDIM + o0 + r) * SEQ + s] = acc[i][j][r] + bs[r];
    }
  }
}

extern "C" void kernel_launch(void* const* d_in, const int* in_sizes, int n_in,
                              void* d_out, int out_size, void* d_ws, size_t ws_size,
                              hipStream_t stream) {
  const float* x      = (const float*)d_in[0];
  const float* w_qkv  = (const float*)d_in[1];
  const float* w_proj = (const float*)d_in[2];
  const float* b_proj = (const float*)d_in[3];
  float* out = (float*)d_out;

  char* ws = (char*)d_ws;
  const size_t SZX = (size_t)NB * SEQ * CDIM * sizeof(u16);       // 6 MB (xT / aT)
  const size_t SZQ = (size_t)NB * NH * SEQ * DP * sizeof(u16);    // 8 MB (padded Q/K)
  const size_t SZV = (size_t)NB * NH * SEQ * DH * sizeof(u16);    // 6 MB
  u16* xT   = (u16*)(ws);
  u16* qws  = (u16*)(ws + SZX);
  u16* kws  = (u16*)(ws + SZX + SZQ);
  u16* vws  = (u16*)(ws + SZX + 2 * SZQ);
  u16* wq_b = (u16*)(ws + SZX + 2 * SZQ + SZV);
  u16* wp_b = wq_b + (size_t)3 * CDIM * CDIM;
  u16* aT   = xT;

  const int n_all = 4 * CDIM * CDIM;
  cvt_weights<<<dim3(n_all / 4 / 256), 256, 0, stream>>>(w_qkv, w_proj, wq_b);
  transpose_x<<<dim3(16, 6, 8), 256, 0, stream>>>(x, xT);
  qkv_kernel<<<dim3(8, 9, 8), 256, 0, stream>>>(wq_b, xT, qws, kws, vws);
  attn_kernel<<<dim3(8, 64), 256, 0, stream>>>(qws, kws, vws, aT);
  proj_kernel<<<dim3(8, 3, 8), 256, 0, stream>>>(wp_b, aT, b_proj, out);
}

// Round 7
// 136.436 us; speedup vs baseline: 1.0830x; 1.0694x over previous
//
#include <hip/hip_runtime.h>
#include <math.h>

typedef unsigned short u16;
typedef __attribute__((ext_vector_type(8))) short short8;
typedef __attribute__((ext_vector_type(8))) unsigned short ushort8;
typedef __attribute__((ext_vector_type(4))) float floatx4;
typedef __attribute__((ext_vector_type(2))) unsigned int uint2v;

#define SEQ 1024
#define CDIM 384
#define NH 8
#define DH 48
#define DP 64   // padded head dim for Q/K storage
#define NB 8

__device__ __forceinline__ u16 f2bf(float f){
  unsigned int u; __builtin_memcpy(&u, &f, 4);
  u = (u + 0x7fffu + ((u >> 16) & 1u)) >> 16;
  return (u16)u;
}
// pack two fp32 -> two bf16 (RTNE) in one u32: low16 = a, high16 = b
__device__ __forceinline__ unsigned packbf(float a, float b){
  unsigned ua, ub; __builtin_memcpy(&ua, &a, 4); __builtin_memcpy(&ub, &b, 4);
  ua += 0x7fffu + ((ua >> 16) & 1u);
  ub += 0x7fffu + ((ub >> 16) & 1u);
  return __builtin_amdgcn_perm(ub, ua, 0x07060302);
}
__device__ __forceinline__ void async16(const u16* g, u16* l){
  __builtin_amdgcn_global_load_lds((const __attribute__((address_space(1))) void*)g,
                                   (__attribute__((address_space(3))) void*)l, 16, 0, 0);
}

// ---------------- Kernel 1: fused prep ----------------
// blocks [0,768): transpose x[b][c][s] (fp32) -> xT[b][s][c] (bf16), LDS-tiled
// blocks [768,1344): fp32 -> bf16 conversion of both weight matrices
__global__ __launch_bounds__(256) void prep_kernel(const float* __restrict__ x,
                                                   const float* __restrict__ wq,
                                                   const float* __restrict__ wp,
                                                   u16* __restrict__ xT,
                                                   u16* __restrict__ wdst){
  __shared__ u16 ldsT[64 * 72];
  const int id = blockIdx.x;
  const int t = threadIdx.x;
  if (id < 768){
    const int bx = id & 15, by = (id >> 4) % 6, bz = id / 96;
    const int c0 = by * 64;
    const int s0 = bx * 64;
    const int rr = t >> 2, q4 = t & 3;

    const float* src = x + ((size_t)(bz * CDIM + c0 + rr)) * SEQ + s0;
#pragma unroll
    for (int i = 0; i < 4; i++){
      const int cc = q4 + i * 4;
      float4 f = *(const float4*)(src + cc * 4);
      ldsT[(cc * 4 + 0) * 72 + rr] = f2bf(f.x);
      ldsT[(cc * 4 + 1) * 72 + rr] = f2bf(f.y);
      ldsT[(cc * 4 + 2) * 72 + rr] = f2bf(f.z);
      ldsT[(cc * 4 + 3) * 72 + rr] = f2bf(f.w);
    }
    __syncthreads();
    u16* dst = xT + ((size_t)(bz * SEQ + s0 + rr)) * CDIM + c0 + q4 * 16;
    *(ushort8*)(dst)     = *(const ushort8*)&ldsT[rr * 72 + q4 * 16];
    *(ushort8*)(dst + 8) = *(const ushort8*)&ldsT[rr * 72 + q4 * 16 + 8];
  } else {
    const int NWQ = 3 * CDIM * CDIM;  // 442368
    const int i = ((id - 768) * 256 + t) * 4;
    const float* src = (i < NWQ) ? (wq + i) : (wp + (i - NWQ));
    float4 f = *(const float4*)src;
    uint2v v; v[0] = packbf(f.x, f.y); v[1] = packbf(f.z, f.w);
    *(uint2v*)(wdst + i) = v;
  }
}

// ---------------- Kernel 2: QKV GEMM (128x128 tile, BK=64, async swizzled staging) ----------------
__global__ __launch_bounds__(256) void qkv_kernel(const u16* __restrict__ W,
                                                  const u16* __restrict__ xT,
                                                  u16* __restrict__ qws,
                                                  u16* __restrict__ kws,
                                                  u16* __restrict__ vws){
  __shared__ u16 ldsA[128 * 64];
  __shared__ u16 ldsB[128 * 64];
  const int t = threadIdx.x;
  const int w = t >> 6, l = t & 63;
  const int quad = l >> 4, li = l & 15;
  const int wm = w >> 1, wn = w & 1;
  const int n0 = blockIdx.x * 128;
  const int m0 = blockIdx.y * 128;
  const int b  = blockIdx.z;

  floatx4 acc[4][4];
#pragma unroll
  for (int i = 0; i < 4; i++)
#pragma unroll
    for (int j = 0; j < 4; j++) acc[i][j] = (floatx4)0.0f;

  const u16* xb = xT + (size_t)b * SEQ * CDIM;
  const int swz = li & 7;

  for (int kk = 0; kk < CDIM; kk += 64){
    __syncthreads();
#pragma unroll
    for (int rep = 0; rep < 4; rep++){
      const int cs = rep * 256 + t;
      const int row = cs >> 3, c4 = cs & 7;
      const int gcol = ((c4 ^ (row & 7)) << 3);
      async16(&W [(size_t)(m0 + row) * CDIM + kk + gcol], &ldsA[cs * 8]);
      async16(&xb[(size_t)(n0 + row) * CDIM + kk + gcol], &ldsB[cs * 8]);
    }
    __syncthreads();
#pragma unroll
    for (int kc = 0; kc < 2; kc++){
      const int rc = ((kc * 4 + quad) ^ swz) << 3;
      short8 af[4], bf[4];
#pragma unroll
      for (int i = 0; i < 4; i++)
        af[i] = *(const short8*)&ldsA[(wm * 64 + i * 16 + li) * 64 + rc];
#pragma unroll
      for (int j = 0; j < 4; j++)
        bf[j] = *(const short8*)&ldsB[(wn * 64 + j * 16 + li) * 64 + rc];
#pragma unroll
      for (int i = 0; i < 4; i++)
#pragma unroll
        for (int j = 0; j < 4; j++)
          acc[i][j] = __builtin_amdgcn_mfma_f32_16x16x32_bf16(af[i], bf[j], acc[i][j], 0, 0, 0);
    }
  }

  const float qs = 0.14433756729740643f * 1.4426950408889634f; // d^-0.5 * log2(e)
  const uint2v z2 = (uint2v)0u;
#pragma unroll
  for (int i = 0; i < 4; i++){
    const int obase = m0 + wm * 64 + i * 16 + quad * 4;
    const int which = obase / CDIM;
    const int rem = obase - which * CDIM;
    const int h = rem / DH;
    const int dd = rem - h * DH;
    const int pair = b * NH + h;
#pragma unroll
    for (int j = 0; j < 4; j++){
      const int s = n0 + wn * 64 + j * 16 + li;
      floatx4 v = acc[i][j];
      if (which == 0){
        uint2v pk; pk[0] = packbf(v[0] * qs, v[1] * qs); pk[1] = packbf(v[2] * qs, v[3] * qs);
        *(uint2v*)&qws[((size_t)pair * SEQ + s) * DP + dd] = pk;
        if ((dd & 48) == 32)
          *(uint2v*)&qws[((size_t)pair * SEQ + s) * DP + dd + 16] = z2;
      } else if (which == 1){
        uint2v pk; pk[0] = packbf(v[0], v[1]); pk[1] = packbf(v[2], v[3]);
        *(uint2v*)&kws[((size_t)pair * SEQ + s) * DP + dd] = pk;
        if ((dd & 48) == 32)
          *(uint2v*)&kws[((size_t)pair * SEQ + s) * DP + dd + 16] = z2;
      } else {
#pragma unroll
        for (int r = 0; r < 4; r++)
          vws[((size_t)pair * DH + dd + r) * SEQ + s] = f2bf(v[r]);
      }
    }
  }
}

// ---------------- Kernel 3: flash attention, S^T form, online-max softmax ----------------
// block = 4 waves x 32 queries = 128 q; KV tiles of 128; grid (8, 64)
__global__ __launch_bounds__(256) void attn_kernel(const u16* __restrict__ qws,
                                                   const u16* __restrict__ kws,
                                                   const u16* __restrict__ vws,
                                                   u16* __restrict__ aT){
  __shared__ u16 ldsK[128 * 64];    // 16 KB, chunk-swizzled ^(row&7)
  __shared__ u16 ldsV[48 * 128];    // 12 KB, chunk-swizzled ^(row&15)
  __shared__ u16 ldsP[128 * 136];   // 34 KB, padded stride

  const int t = threadIdx.x;
  const int w = t >> 6, l = t & 63;
  const int quad = l >> 4, li = l & 15;
  const int pair = blockIdx.y;
  const int b = pair >> 3, h = pair & 7;
  const int qbase = blockIdx.x * 128 + w * 32;
  const int swz = li & 7;

  short8 qf[2][2];
#pragma unroll
  for (int mt = 0; mt < 2; mt++){
    const u16* qrow = qws + ((size_t)pair * SEQ + qbase + mt * 16 + li) * DP;
    qf[mt][0] = *(const short8*)(qrow + quad * 8);
    qf[mt][1] = *(const short8*)(qrow + 32 + quad * 8);
  }

  floatx4 ot[3][2];
#pragma unroll
  for (int dt = 0; dt < 3; dt++)
#pragma unroll
    for (int mt = 0; mt < 2; mt++) ot[dt][mt] = (floatx4)0.0f;
  float m_run[2] = {-3.0e38f, -3.0e38f};
  float l_run[2] = {0.0f, 0.0f};

  const u16* kbase = kws + (size_t)pair * SEQ * DP;
  const u16* vbase = vws + (size_t)pair * DH * SEQ;

  for (int kv0 = 0; kv0 < SEQ; kv0 += 128){
    __syncthreads();
#pragma unroll
    for (int rep = 0; rep < 4; rep++){
      const int cs = rep * 256 + t;
      const int row = cs >> 3, c4 = cs & 7;
      async16(&kbase[(size_t)(kv0 + row) * DP + ((c4 ^ (row & 7)) << 3)], &ldsK[cs * 8]);
    }
#pragma unroll
    for (int rep = 0; rep < 3; rep++){
      const int cs = rep * 256 + t;
      const int row = cs >> 4, c4 = cs & 15;
      async16(&vbase[(size_t)row * SEQ + kv0 + ((c4 ^ (row & 15)) << 3)], &ldsV[cs * 8]);
    }
    __syncthreads();

    // ---- S^T[y][m] = K[y][:] . Q[m][:] ----
    floatx4 st[8][2];
#pragma unroll
    for (int yt = 0; yt < 8; yt++){
      const u16* krow = ldsK + (yt * 16 + li) * 64;
      const short8 kf0 = *(const short8*)(krow + (((0 + quad) ^ swz) << 3));
      const short8 kf1 = *(const short8*)(krow + (((4 + quad) ^ swz) << 3));
#pragma unroll
      for (int mt = 0; mt < 2; mt++){
        floatx4 z = (floatx4)0.0f;
        z = __builtin_amdgcn_mfma_f32_16x16x32_bf16(kf0, qf[mt][0], z, 0, 0, 0);
        z = __builtin_amdgcn_mfma_f32_16x16x32_bf16(kf1, qf[mt][1], z, 0, 0, 0);
        st[yt][mt] = z;
      }
    }

    // ---- online softmax (per-query stats; query = lane&15, quad-reduced) ----
#pragma unroll
    for (int mt = 0; mt < 2; mt++){
      float mx = -3.0e38f;
#pragma unroll
      for (int yt = 0; yt < 8; yt++)
#pragma unroll
        for (int r = 0; r < 4; r++) mx = fmaxf(mx, st[yt][mt][r]);
      mx = fmaxf(mx, __shfl_xor(mx, 16, 64));
      mx = fmaxf(mx, __shfl_xor(mx, 32, 64));
      const float mnew = fmaxf(m_run[mt], mx);
      const float alpha = __builtin_amdgcn_exp2f(m_run[mt] - mnew);
      m_run[mt] = mnew;

      u16* prow = ldsP + (w * 32 + mt * 16 + li) * 136;
      float ls = 0.0f;
#pragma unroll
      for (int yt = 0; yt < 8; yt++){
        float p0 = __builtin_amdgcn_exp2f(st[yt][mt][0] - mnew);
        float p1 = __builtin_amdgcn_exp2f(st[yt][mt][1] - mnew);
        float p2 = __builtin_amdgcn_exp2f(st[yt][mt][2] - mnew);
        float p3 = __builtin_amdgcn_exp2f(st[yt][mt][3] - mnew);
        ls += (p0 + p1) + (p2 + p3);
        uint2v pk; pk[0] = packbf(p0, p1); pk[1] = packbf(p2, p3);
        *(uint2v*)&prow[yt * 16 + quad * 4] = pk;
      }
      l_run[mt] = l_run[mt] * alpha + ls;
#pragma unroll
      for (int dt = 0; dt < 3; dt++) ot[dt][mt] *= alpha;
    }
    __syncthreads();   // P visible before PV reads

    // ---- O^T[d][m] += Vt[d][y] . P[y][m] ----
#pragma unroll
    for (int ks = 0; ks < 128; ks += 32){
      short8 pb[2];
#pragma unroll
      for (int mt = 0; mt < 2; mt++)
        pb[mt] = *(const short8*)&ldsP[(w * 32 + mt * 16 + li) * 136 + ks + quad * 8];
#pragma unroll
      for (int dt = 0; dt < 3; dt++){
        const short8 vf = *(const short8*)&ldsV[(dt * 16 + li) * 128 +
                                                ((((ks >> 3) + quad) ^ li) << 3)];
#pragma unroll
        for (int mt = 0; mt < 2; mt++)
          ot[dt][mt] = __builtin_amdgcn_mfma_f32_16x16x32_bf16(vf, pb[mt], ot[dt][mt], 0, 0, 0);
      }
    }
  }

  // cross-quad l reduction and write-out
#pragma unroll
  for (int mt = 0; mt < 2; mt++){
    float ls = l_run[mt];
    ls += __shfl_xor(ls, 16, 64);
    ls += __shfl_xor(ls, 32, 64);
    const float rl = 1.0f / ls;
    const int q = qbase + mt * 16 + li;
#pragma unroll
    for (int dt = 0; dt < 3; dt++){
      floatx4 v = ot[dt][mt];
      uint2v pk; pk[0] = packbf(v[0] * rl, v[1] * rl); pk[1] = packbf(v[2] * rl, v[3] * rl);
      *(uint2v*)&aT[((size_t)b * SEQ + q) * CDIM + h * DH + dt * 16 + quad * 4] = pk;
    }
  }
}

// ---------------- Kernel 4: proj GEMM (128x128 tile, BK=64, async), fp32 out + bias ----------------
__global__ __launch_bounds__(256) void proj_kernel(const u16* __restrict__ W,
                                                   const u16* __restrict__ aT,
                                                   const float* __restrict__ bias,
                                                   float* __restrict__ out){
  __shared__ u16 ldsA[128 * 64];
  __shared__ u16 ldsB[128 * 64];
  const int t = threadIdx.x;
  const int w = t >> 6, l = t & 63;
  const int quad = l >> 4, li = l & 15;
  const int wm = w >> 1, wn = w & 1;
  const int n0 = blockIdx.x * 128;
  const int m0 = blockIdx.y * 128;
  const int b  = blockIdx.z;

  floatx4 acc[4][4];
#pragma unroll
  for (int i = 0; i < 4; i++)
#pragma unroll
    for (int j = 0; j < 4; j++) acc[i][j] = (floatx4)0.0f;

  const u16* ab = aT + (size_t)b * SEQ * CDIM;
  const int swz = li & 7;

  for (int kk = 0; kk < CDIM; kk += 64){
    __syncthreads();
#pragma unroll
    for (int rep = 0; rep < 4; rep++){
      const int cs = rep * 256 + t;
      const int row = cs >> 3, c4 = cs & 7;
      const int gcol = ((c4 ^ (row & 7)) << 3);
      async16(&W [(size_t)(m0 + row) * CDIM + kk + gcol], &ldsA[cs * 8]);
      async16(&ab[(size_t)(n0 + row) * CDIM + kk + gcol], &ldsB[cs * 8]);
    }
    __syncthreads();
#pragma unroll
    for (int kc = 0; kc < 2; kc++){
      const int rc = ((kc * 4 + quad) ^ swz) << 3;
      short8 af[4], bf[4];
#pragma unroll
      for (int i = 0; i < 4; i++)
        af[i] = *(const short8*)&ldsA[(wm * 64 + i * 16 + li) * 64 + rc];
#pragma unroll
      for (int j = 0; j < 4; j++)
        bf[j] = *(const short8*)&ldsB[(wn * 64 + j * 16 + li) * 64 + rc];
#pragma unroll
      for (int i = 0; i < 4; i++)
#pragma unroll
        for (int j = 0; j < 4; j++)
          acc[i][j] = __builtin_amdgcn_mfma_f32_16x16x32_bf16(af[i], bf[j], acc[i][j], 0, 0, 0);
    }
  }

#pragma unroll
  for (int i = 0; i < 4; i++){
    const int o0 = m0 + wm * 64 + i * 16 + quad * 4;
    float bs[4];
#pragma unroll
    for (int r = 0; r < 4; r++) bs[r] = bias[o0 + r];
#pragma unroll
    for (int j = 0; j < 4; j++){
      const int s = n0 + wn * 64 + j * 16 + li;
#pragma unroll
      for (int r = 0; r < 4; r++)
        out[((size_t)b * CDIM + o0 + r) * SEQ + s] = acc[i][j][r] + bs[r];
    }
  }
}

extern "C" void kernel_launch(void* const* d_in, const int* in_sizes, int n_in,
                              void* d_out, int out_size, void* d_ws, size_t ws_size,
                              hipStream_t stream) {
  const float* x      = (const float*)d_in[0];
  const float* w_qkv  = (const float*)d_in[1];
  const float* w_proj = (const float*)d_in[2];
  const float* b_proj = (const float*)d_in[3];
  float* out = (float*)d_out;

  char* ws = (char*)d_ws;
  const size_t SZX = (size_t)NB * SEQ * CDIM * sizeof(u16);       // 6 MB (xT / aT)
  const size_t SZQ = (size_t)NB * NH * SEQ * DP * sizeof(u16);    // 8 MB (padded Q/K)
  const size_t SZV = (size_t)NB * NH * SEQ * DH * sizeof(u16);    // 6 MB
  u16* xT   = (u16*)(ws);
  u16* qws  = (u16*)(ws + SZX);
  u16* kws  = (u16*)(ws + SZX + SZQ);
  u16* vws  = (u16*)(ws + SZX + 2 * SZQ);
  u16* wq_b = (u16*)(ws + SZX + 2 * SZQ + SZV);
  u16* wp_b = wq_b + (size_t)3 * CDIM * CDIM;
  u16* aT   = xT;

  prep_kernel<<<dim3(768 + 576), 256, 0, stream>>>(x, w_qkv, w_proj, xT, wq_b);
  qkv_kernel<<<dim3(8, 9, 8), 256, 0, stream>>>(wq_b, xT, qws, kws, vws);
  attn_kernel<<<dim3(8, 64), 256, 0, stream>>>(qws, kws, vws, aT);
  proj_kernel<<<dim3(8, 3, 8), 256, 0, stream>>>(wp_b, aT, b_proj, out);
}